// Round 14
// baseline (477.369 us; speedup 1.0000x reference)
//
#include <hip/hip_runtime.h>
#include <math.h>
#include <stdint.h>

typedef __bf16 bf16_t;
typedef __bf16 bf16x8 __attribute__((ext_vector_type(8)));
typedef float f32x4 __attribute__((ext_vector_type(4)));
typedef unsigned short ushort8_t __attribute__((ext_vector_type(8)));
typedef unsigned short ushort4_t __attribute__((ext_vector_type(4)));

#define LOG2E 1.44269504088896340736f

__device__ inline unsigned short f2bf_bits(float f) {
  union { float f; unsigned int u; } v; v.f = f;
  unsigned int u = v.u;
  return (unsigned short)((u + 0x7fffu + ((u >> 16) & 1u)) >> 16);
}

// global -> LDS direct copy, 16B per lane. LDS dest is wave-uniform base
// + lane*16 (HW behavior, m104); global src is per-lane.
__device__ inline void gld_lds16(const void* g, void* l) {
  __builtin_amdgcn_global_load_lds(
      (__attribute__((address_space(1))) void*)(uintptr_t)(g),
      (__attribute__((address_space(3))) void*)(uintptr_t)(l),
      16, 0, 0);
}

// ---------------- cast fp32 -> bf16 (weights) ----------------
__global__ __launch_bounds__(256) void cast_kernel(const float* __restrict__ in,
                                                   unsigned short* __restrict__ out,
                                                   int n) {
  int i = (blockIdx.x * 256 + threadIdx.x) * 4;
  if (i >= n) return;
  float4 f = *reinterpret_cast<const float4*>(in + i);
  ushort4_t o;
  o[0] = f2bf_bits(f.x); o[1] = f2bf_bits(f.y);
  o[2] = f2bf_bits(f.z); o[3] = f2bf_bits(f.w);
  *reinterpret_cast<ushort4_t*>(out + i) = o;
}

// ---------------- LayerNorm (C=1024) + cast to bf16 ----------------
__global__ __launch_bounds__(256) void ln_kernel(const float* __restrict__ x,
                                                 const float* __restrict__ g,
                                                 const float* __restrict__ bta,
                                                 unsigned short* __restrict__ out) {
  const int row = blockIdx.x;
  const int c = threadIdx.x * 4;
  const float4 xv = *reinterpret_cast<const float4*>(x + (size_t)row * 1024 + c);
  float s = xv.x + xv.y + xv.z + xv.w;
  float sq = xv.x * xv.x + xv.y * xv.y + xv.z * xv.z + xv.w * xv.w;
#pragma unroll
  for (int xm = 1; xm < 64; xm <<= 1) {
    s += __shfl_xor(s, xm, 64);
    sq += __shfl_xor(sq, xm, 64);
  }
  __shared__ float sh[8];
  const int wave = threadIdx.x >> 6, lane = threadIdx.x & 63;
  if (lane == 0) { sh[wave] = s; sh[4 + wave] = sq; }
  __syncthreads();
  const float ts = sh[0] + sh[1] + sh[2] + sh[3];
  const float tq = sh[4] + sh[5] + sh[6] + sh[7];
  const float mean = ts * (1.0f / 1024.0f);
  const float var = tq * (1.0f / 1024.0f) - mean * mean;
  const float rstd = rsqrtf(var + 1e-5f);
  const float4 gv = *reinterpret_cast<const float4*>(g + c);
  const float4 bv = *reinterpret_cast<const float4*>(bta + c);
  ushort4_t o;
  o[0] = f2bf_bits((xv.x - mean) * rstd * gv.x + bv.x);
  o[1] = f2bf_bits((xv.y - mean) * rstd * gv.y + bv.y);
  o[2] = f2bf_bits((xv.z - mean) * rstd * gv.z + bv.z);
  o[3] = f2bf_bits((xv.w - mean) * rstd * gv.w + bv.w);
  *reinterpret_cast<ushort4_t*>(out + (size_t)row * 1024 + c) = o;
}

// ---------------- GEMM: faithful m97 replica (R14) --------------------------
// R13 post-mortem: T1 grid swizzle HURT (FETCH 78->140MB, 577->501 TF) —
// reverted. Pointer hoisting left VALUBusy at 57% — remat was not the cost.
// New diagnosis vs m97's verified 874 TF: m97 is BK=32 — each acc register
// is written ONCE per K-tile, so no two MFMAs on the same accumulator are
// adjacent. My BK=64 loop wrote each acc twice back-to-back (16 dependent
// MFMA pairs/K-tile, each paying full MFMA latency ~2x throughput, m119).
// R14 = m97 exactly: BK=32, 16 KiB LDS, 4 waves (2Mx2N), per-wave 64x64,
// per K-tile {4 gld_lds -> sync -> 8 ds_read_b128 -> 16 INDEPENDENT MFMAs
// -> sync}, plain __syncthreads, no inline asm, default blockIdx order.
// Kept from the ladder: BK=32-adapted XOR swizzle on 16B col-groups:
//   read col-group cg = lk ^ ((row>>1)&3)  (row>>1 since rows are 64B = 16
//   banks; XOR on cg spreads 8 rows over all 32 banks -> 8 words/bank =
//   the wave64-b128 minimum; verified bank walk in notes).
//   staging source col-group = (t&3) ^ ((t>>3)&3) (same involution:
//   dest row = p*64 + (t>>2), (row>>1)&3 == (t>>3)&3).
template <int EPI>  // 0 = bias->bf16; 1 = bias+res->f32; 2 = bias+GELU->bf16
__global__ __launch_bounds__(256) void gemmS(const unsigned short* __restrict__ A,
                                             const unsigned short* __restrict__ W,
                                             const float* __restrict__ bias,
                                             const float* __restrict__ res,
                                             unsigned short* __restrict__ outb,
                                             float* __restrict__ outf,
                                             int N, int K) {
  __shared__ unsigned short lds[2 * 128 * 32];  // 16 KiB: A[128][32], B[128][32]
  const int tid = threadIdx.x;
  const int wave = tid >> 6, l = tid & 63;
  const int m0 = blockIdx.y * 128, n0 = blockIdx.x * 128;
  const int wm = wave >> 1, wn = wave & 1;   // 2x2 wave grid
  const int lr16 = l & 15, lk = l >> 4;

  // hoisted read bases: col-group cg = lk ^ ((lr16>>1)&3)  (lane-constant;
  // frag rows are wm*64 + mi*16 + lr16 and mi*16 doesn't touch (row>>1)&3)
  const int cgr = (lk ^ ((lr16 >> 1) & 3)) * 8;  // elems
  const unsigned short* pa = &lds[(wm * 64 + lr16) * 32 + cgr];
  const unsigned short* pb = &lds[4096 + (wn * 64 + lr16) * 32 + cgr];

  // hoisted staging pointers (row*K once; += 32 per tile). dest linear.
  const int strow = tid >> 2;                       // 0..63, + p*64
  const int sx = (((tid & 3) ^ ((tid >> 3) & 3)) << 3);  // pre-swizzled src col
  const unsigned short* pA0 = A + (size_t)(m0 + strow) * K + sx;
  const unsigned short* pA1 = A + (size_t)(m0 + 64 + strow) * K + sx;
  const unsigned short* pB0 = W + (size_t)(n0 + strow) * K + sx;
  const unsigned short* pB1 = W + (size_t)(n0 + 64 + strow) * K + sx;
  const int ldst = tid * 8;  // shorts (16B per thread)

  f32x4 acc[4][4];
#pragma unroll
  for (int i = 0; i < 4; ++i)
#pragma unroll
    for (int j = 0; j < 4; ++j) { f32x4 z = {0.f, 0.f, 0.f, 0.f}; acc[i][j] = z; }

  const int nt = K / 32;
  for (int t = 0; t < nt; ++t) {
    gld_lds16(pA0, &lds[ldst]);
    gld_lds16(pA1, &lds[2048 + ldst]);
    gld_lds16(pB0, &lds[4096 + ldst]);
    gld_lds16(pB1, &lds[6144 + ldst]);
    pA0 += 32; pA1 += 32; pB0 += 32; pB1 += 32;
    __syncthreads();  // compiler emits the vmcnt/lgkm drain here

    bf16x8 af[4], bfr[4];
#pragma unroll
    for (int mi = 0; mi < 4; ++mi)
      af[mi] = *reinterpret_cast<const bf16x8*>(pa + mi * 512);
#pragma unroll
    for (int ni = 0; ni < 4; ++ni)
      bfr[ni] = *reinterpret_cast<const bf16x8*>(pb + ni * 512);
    // 16 independent MFMAs: each acc written exactly once per K-tile (m97)
#pragma unroll
    for (int mi = 0; mi < 4; ++mi)
#pragma unroll
      for (int ni = 0; ni < 4; ++ni)
        acc[mi][ni] =
            __builtin_amdgcn_mfma_f32_16x16x32_bf16(af[mi], bfr[ni], acc[mi][ni], 0, 0, 0);
    __syncthreads();  // all reads done before next tile's gld_lds overwrites
  }

  // epilogue: C row=(l>>4)*4+r, col=l&15 per 16x16 fragment (m89/m91)
#pragma unroll
  for (int ni = 0; ni < 4; ++ni) {
    const int col = n0 + wn * 64 + ni * 16 + lr16;
    const float bv = bias[col];
#pragma unroll
    for (int mi = 0; mi < 4; ++mi) {
#pragma unroll
      for (int r = 0; r < 4; ++r) {
        const int row = m0 + wm * 64 + mi * 16 + lk * 4 + r;
        const size_t idx = (size_t)row * N + col;
        float v = acc[mi][ni][r] + bv;
        if (EPI == 0) {
          outb[idx] = f2bf_bits(v);
        } else if (EPI == 1) {
          outf[idx] = v + res[idx];
        } else {
          v = 0.5f * v * (1.0f + erff(v * 0.70710678118654752f));
          outb[idx] = f2bf_bits(v);
        }
      }
    }
  }
}

// ---------------- causal flash attention v2 (paired q-tiles) ----------------
__device__ inline int swz(int row, int colelem) {
  return row * 64 + (colelem ^ ((row & 7) << 3));
}

__global__ __launch_bounds__(256) void attn_kernel(const unsigned short* __restrict__ kqv,
                                                   unsigned short* __restrict__ y) {
  __shared__ unsigned short Ks[2][64 * 64];
  __shared__ unsigned short Vt[2][64 * 64];
  __shared__ unsigned short Ps[4][16 * 64];

  const int tid = threadIdx.x;
  const int wave = tid >> 6;
  const int lane = tid & 63;
  const int bh = blockIdx.x;
  const int pair = blockIdx.y;
  const int b = bh >> 4;
  const int h = bh & 15;
  const int lo = pair;
  const int hi = 15 - pair;
  const int bT = b * 1024;
  const int hoff = h * 192;

  auto loadq = [&](int q0t, bf16x8 (&qf)[2]) {
    const unsigned short* qp =
        kqv + (size_t)(bT + q0t + wave * 16 + (lane & 15)) * 3072 + hoff + 64 +
        (lane >> 4) * 8;
#pragma unroll
    for (int kk = 0; kk < 2; ++kk) {
      bf16x8 t = *reinterpret_cast<const bf16x8*>(qp + kk * 32);
#pragma unroll
      for (int e = 0; e < 8; ++e) t[e] = (bf16_t)((float)t[e] * 0.125f);
      qf[kk] = t;
    }
  };

  auto stageK = [&](int j0, int bufi) {
#pragma unroll
    for (int i = 0; i < 2; ++i) {
      const int off = i * 4096 + wave * 1024 + lane * 16;
      const int jr = off >> 7;
      const int ce = ((off & 127) >> 1) ^ ((jr & 7) << 3);
      gld_lds16(kqv + (size_t)(bT + j0 + jr) * 3072 + hoff + ce,
                &Ks[bufi][i * 2048 + wave * 512]);
    }
  };

  ushort8_t vreg0, vreg1;
  auto vload = [&](int j0) {
    const unsigned short* vp =
        kqv + (size_t)(bT + j0 + (tid & 63)) * 3072 + hoff + 128 + (tid >> 6) * 8;
    vreg0 = *reinterpret_cast<const ushort8_t*>(vp);
    vreg1 = *reinterpret_cast<const ushort8_t*>(vp + 32);
  };
  auto vwrite = [&](int bufi) {
    const int j = tid & 63;
    const int dg = tid >> 6;
#pragma unroll
    for (int e = 0; e < 8; ++e) Vt[bufi][swz(dg * 8 + e, j)] = vreg0[e];
#pragma unroll
    for (int e = 0; e < 8; ++e) Vt[bufi][swz((dg + 4) * 8 + e, j)] = vreg1[e];
  };

  auto compute = [&](const bf16x8 (&qf)[2], f32x4 (&acc_o)[4], float (&mr)[4],
                     float (&lr)[4], int q0t, int j0, bool diag, int cur) {
    f32x4 s[4];
#pragma unroll
    for (int nt = 0; nt < 4; ++nt) {
      f32x4 a = {0.f, 0.f, 0.f, 0.f};
#pragma unroll
      for (int kk = 0; kk < 2; ++kk) {
        const bf16x8 kf = *reinterpret_cast<const bf16x8*>(
            &Ks[cur][swz(nt * 16 + (lane & 15), kk * 32 + (lane >> 4) * 8)]);
        a = __builtin_amdgcn_mfma_f32_16x16x32_bf16(qf[kk], kf, a, 0, 0, 0);
      }
      s[nt] = a;
    }
#pragma unroll
    for (int r = 0; r < 4; ++r) {
      float mx = -1e30f;
      if (diag) {
        const int qg = q0t + wave * 16 + ((lane >> 4) << 2) + r;
#pragma unroll
        for (int nt = 0; nt < 4; ++nt) {
          const int jg = j0 + nt * 16 + (lane & 15);
          const float sv = (jg <= qg) ? s[nt][r] : -1e30f;
          s[nt][r] = sv;
          mx = fmaxf(mx, sv);
        }
      } else {
#pragma unroll
        for (int nt = 0; nt < 4; ++nt) mx = fmaxf(mx, s[nt][r]);
      }
#pragma unroll
      for (int xm = 1; xm < 16; xm <<= 1) mx = fmaxf(mx, __shfl_xor(mx, xm, 64));
      const float mnew = fmaxf(mr[r], mx);
      const float sc = exp2f((mr[r] - mnew) * LOG2E);
      mr[r] = mnew;
      float ssum = 0.f;
#pragma unroll
      for (int nt = 0; nt < 4; ++nt) {
        const float p = exp2f((s[nt][r] - mnew) * LOG2E);
        s[nt][r] = p;
        ssum += p;
      }
#pragma unroll
      for (int xm = 1; xm < 16; xm <<= 1) ssum += __shfl_xor(ssum, xm, 64);
      lr[r] = lr[r] * sc + ssum;
#pragma unroll
      for (int dt = 0; dt < 4; ++dt) acc_o[dt][r] *= sc;
    }
    unsigned short* Pw = &Ps[wave][0];
#pragma unroll
    for (int nt = 0; nt < 4; ++nt)
#pragma unroll
      for (int r = 0; r < 4; ++r)
        Pw[swz(((lane >> 4) << 2) + r, nt * 16 + (lane & 15))] = f2bf_bits(s[nt][r]);
#pragma unroll
    for (int kk = 0; kk < 2; ++kk) {
      const bf16x8 pf = *reinterpret_cast<const bf16x8*>(
          &Ps[wave][swz(lane & 15, kk * 32 + (lane >> 4) * 8)]);
#pragma unroll
      for (int dt = 0; dt < 4; ++dt) {
        const bf16x8 vf = *reinterpret_cast<const bf16x8*>(
            &Vt[cur][swz(dt * 16 + (lane & 15), kk * 32 + (lane >> 4) * 8)]);
        acc_o[dt] = __builtin_amdgcn_mfma_f32_16x16x32_bf16(pf, vf, acc_o[dt], 0, 0, 0);
      }
    }
  };

  auto writeo = [&](int q0t, f32x4 (&acc_o)[4], float (&lr)[4]) {
#pragma unroll
    for (int dt = 0; dt < 4; ++dt)
#pragma unroll
      for (int r = 0; r < 4; ++r) {
        const int qg = q0t + wave * 16 + ((lane >> 4) << 2) + r;
        y[(size_t)(bT + qg) * 1024 + h * 64 + dt * 16 + (lane & 15)] =
            f2bf_bits(acc_o[dt][r] / lr[r]);
      }
  };

  bf16x8 qf_l[2], qf_h[2];
  loadq(lo * 64, qf_l);
  loadq(hi * 64, qf_h);
  f32x4 acc_l[4], acc_h[4];
#pragma unroll
  for (int dt = 0; dt < 4; ++dt) {
    f32x4 z = {0.f, 0.f, 0.f, 0.f};
    acc_l[dt] = z;
    acc_h[dt] = z;
  }
  float mr_l[4] = {-1e30f, -1e30f, -1e30f, -1e30f};
  float mr_h[4] = {-1e30f, -1e30f, -1e30f, -1e30f};
  float lr_l[4] = {0.f, 0.f, 0.f, 0.f};
  float lr_h[4] = {0.f, 0.f, 0.f, 0.f};

  stageK(0, 0);
  vload(0);
  vwrite(0);

  for (int jt = 0; jt <= hi; ++jt) {
    const int cur = jt & 1;
    __syncthreads();  // drains vmcnt/lgkm: buf[cur] ready; buf[cur^1] free
    if (jt < hi) {
      stageK((jt + 1) * 64, cur ^ 1);
      vload((jt + 1) * 64);
    }
    compute(qf_h, acc_h, mr_h, lr_h, hi * 64, jt * 64, jt == hi, cur);
    if (jt <= lo)
      compute(qf_l, acc_l, mr_l, lr_l, lo * 64, jt * 64, jt == lo, cur);
    if (jt < hi) vwrite(cur ^ 1);
  }

  writeo(hi * 64, acc_h, lr_h);
  writeo(lo * 64, acc_l, lr_l);
}

// ---------------- launch ----------------
extern "C" void kernel_launch(void* const* d_in, const int* in_sizes, int n_in,
                              void* d_out, int out_size, void* d_ws, size_t ws_size,
                              hipStream_t stream) {
  const float* x = (const float*)d_in[0];
  const float* kqv_w = (const float*)d_in[1];
  const float* kqv_b = (const float*)d_in[2];
  const float* proj_w = (const float*)d_in[3];
  const float* proj_b = (const float*)d_in[4];
  const float* ln1_g = (const float*)d_in[5];
  const float* ln1_b = (const float*)d_in[6];
  const float* ln2_g = (const float*)d_in[7];
  const float* ln2_b = (const float*)d_in[8];
  const float* fc1_w = (const float*)d_in[9];
  const float* fc1_b = (const float*)d_in[10];
  const float* fc2_w = (const float*)d_in[11];
  const float* fc2_b = (const float*)d_in[12];
  float* out = (float*)d_out;

  char* ws = (char*)d_ws;
  size_t off = 0;
  auto alloc = [&](size_t bytes) {
    char* p = ws + off;
    off += (bytes + 255) & ~(size_t)255;
    return p;
  };
  unsigned short* wk = (unsigned short*)alloc((size_t)3072 * 1024 * 2);
  unsigned short* wp = (unsigned short*)alloc((size_t)1024 * 1024 * 2);
  unsigned short* w1 = (unsigned short*)alloc((size_t)4096 * 1024 * 2);
  unsigned short* w2 = (unsigned short*)alloc((size_t)4096 * 1024 * 2);
  unsigned short* hbuf = (unsigned short*)alloc((size_t)8192 * 1024 * 2);
  unsigned short* kqvb = (unsigned short*)alloc((size_t)8192 * 3072 * 2);
  unsigned short* yb = (unsigned short*)alloc((size_t)8192 * 1024 * 2);
  float* x1 = (float*)alloc((size_t)8192 * 1024 * 4);
  unsigned short* a1 = (unsigned short*)alloc((size_t)8192 * 4096 * 2);

  // cast weights to bf16
  cast_kernel<<<dim3(3072 * 1024 / 1024), 256, 0, stream>>>(kqv_w, wk, 3072 * 1024);
  cast_kernel<<<dim3(1024 * 1024 / 1024), 256, 0, stream>>>(proj_w, wp, 1024 * 1024);
  cast_kernel<<<dim3(4096 * 1024 / 1024), 256, 0, stream>>>(fc1_w, w1, 4096 * 1024);
  cast_kernel<<<dim3(4096 * 1024 / 1024), 256, 0, stream>>>(fc2_w, w2, 4096 * 1024);

  // LN1 -> h (bf16)
  ln_kernel<<<dim3(8192), 256, 0, stream>>>(x, ln1_g, ln1_b, hbuf);

  // kqv = h @ kqv_w^T + b   [8192 x 3072]   grid (24,64)=1536
  gemmS<0><<<dim3(3072 / 128, 8192 / 128), 256, 0, stream>>>(
      hbuf, wk, kqv_b, nullptr, kqvb, nullptr, 3072, 1024);

  // attention -> y (bf16)
  attn_kernel<<<dim3(128, 8), 256, 0, stream>>>(kqvb, yb);

  // x1 = x + y @ proj_w^T + b   (fp32)   grid (8,64)=512
  gemmS<1><<<dim3(1024 / 128, 8192 / 128), 256, 0, stream>>>(
      yb, wp, proj_b, x, nullptr, x1, 1024, 1024);

  // LN2 -> h (bf16, reuse)
  ln_kernel<<<dim3(8192), 256, 0, stream>>>(x1, ln2_g, ln2_b, hbuf);

  // a1 = gelu(h @ fc1_w^T + b)  [8192 x 4096]   grid (32,64)=2048
  gemmS<2><<<dim3(4096 / 128, 8192 / 128), 256, 0, stream>>>(
      hbuf, w1, fc1_b, nullptr, a1, nullptr, 4096, 1024);

  // out = x1 + a1 @ fc2_w^T + b  (fp32)  grid (8,64)=512, K=4096
  gemmS<1><<<dim3(1024 / 128, 8192 / 128), 256, 0, stream>>>(
      a1, w2, fc2_b, x1, nullptr, out, 1024, 4096);
}

// Round 15
// 459.179 us; speedup vs baseline: 1.0396x; 1.0396x over previous
//
#include <hip/hip_runtime.h>
#include <math.h>
#include <stdint.h>

typedef __bf16 bf16_t;
typedef __bf16 bf16x8 __attribute__((ext_vector_type(8)));
typedef float f32x4 __attribute__((ext_vector_type(4)));
typedef float f32x16 __attribute__((ext_vector_type(16)));
typedef unsigned short ushort8_t __attribute__((ext_vector_type(8)));
typedef unsigned short ushort4_t __attribute__((ext_vector_type(4)));

#define LOG2E 1.44269504088896340736f

__device__ inline unsigned short f2bf_bits(float f) {
  union { float f; unsigned int u; } v; v.f = f;
  unsigned int u = v.u;
  return (unsigned short)((u + 0x7fffu + ((u >> 16) & 1u)) >> 16);
}

// global -> LDS direct copy, 16B per lane. LDS dest is wave-uniform base
// + lane*16 (HW behavior, m104); global src is per-lane.
__device__ inline void gld_lds16(const void* g, void* l) {
  __builtin_amdgcn_global_load_lds(
      (__attribute__((address_space(1))) void*)(uintptr_t)(g),
      (__attribute__((address_space(3))) void*)(uintptr_t)(l),
      16, 0, 0);
}

#define BAR() __builtin_amdgcn_s_barrier()
#define LGKM0() asm volatile("s_waitcnt lgkmcnt(0)" ::: "memory")
#define VMW(n) asm volatile("s_waitcnt vmcnt(" #n ")" ::: "memory")
#define PRIO(p) __builtin_amdgcn_s_setprio(p)

// ---------------- cast fp32 -> bf16 (weights) ----------------
__global__ __launch_bounds__(256) void cast_kernel(const float* __restrict__ in,
                                                   unsigned short* __restrict__ out,
                                                   int n) {
  int i = (blockIdx.x * 256 + threadIdx.x) * 4;
  if (i >= n) return;
  float4 f = *reinterpret_cast<const float4*>(in + i);
  ushort4_t o;
  o[0] = f2bf_bits(f.x); o[1] = f2bf_bits(f.y);
  o[2] = f2bf_bits(f.z); o[3] = f2bf_bits(f.w);
  *reinterpret_cast<ushort4_t*>(out + i) = o;
}

// ---------------- LayerNorm (C=1024) + cast to bf16 ----------------
__global__ __launch_bounds__(256) void ln_kernel(const float* __restrict__ x,
                                                 const float* __restrict__ g,
                                                 const float* __restrict__ bta,
                                                 unsigned short* __restrict__ out) {
  const int row = blockIdx.x;
  const int c = threadIdx.x * 4;
  const float4 xv = *reinterpret_cast<const float4*>(x + (size_t)row * 1024 + c);
  float s = xv.x + xv.y + xv.z + xv.w;
  float sq = xv.x * xv.x + xv.y * xv.y + xv.z * xv.z + xv.w * xv.w;
#pragma unroll
  for (int xm = 1; xm < 64; xm <<= 1) {
    s += __shfl_xor(s, xm, 64);
    sq += __shfl_xor(sq, xm, 64);
  }
  __shared__ float sh[8];
  const int wave = threadIdx.x >> 6, lane = threadIdx.x & 63;
  if (lane == 0) { sh[wave] = s; sh[4 + wave] = sq; }
  __syncthreads();
  const float ts = sh[0] + sh[1] + sh[2] + sh[3];
  const float tq = sh[4] + sh[5] + sh[6] + sh[7];
  const float mean = ts * (1.0f / 1024.0f);
  const float var = tq * (1.0f / 1024.0f) - mean * mean;
  const float rstd = rsqrtf(var + 1e-5f);
  const float4 gv = *reinterpret_cast<const float4*>(g + c);
  const float4 bv = *reinterpret_cast<const float4*>(bta + c);
  ushort4_t o;
  o[0] = f2bf_bits((xv.x - mean) * rstd * gv.x + bv.x);
  o[1] = f2bf_bits((xv.y - mean) * rstd * gv.y + bv.y);
  o[2] = f2bf_bits((xv.z - mean) * rstd * gv.z + bv.z);
  o[3] = f2bf_bits((xv.w - mean) * rstd * gv.w + bv.w);
  *reinterpret_cast<ushort4_t*>(out + (size_t)row * 1024 + c) = o;
}

// ---------------- GEMM 128x256, 8 waves, 32x32x16 MFMA (R15) ----------------
// R14 post-mortem: MfmaUtil pinned 21-25% across tile/BK/waves/depth; but
// MfmaUtil+VALUBusy ~= 80% in EVERY run (m97 too: 37+43) -> issue pipes
// saturated; the lever is FLOP per issue slot. 32x32x16 = 2x FLOP/inst,
// higher pipe ceiling (2382 vs 2075 TF, m119/m06), same acc regs (4xf32x16),
// same LDS bytes, HALF the MFMA instructions. Structure = R10 gemm8 verbatim
// (proven: WRITE=ideal no-spill, 0 conflicts, 3-slot ring, VMW(6) counted).
// Layouts: C/D col=l&31, row=(reg&3)+8*(reg>>2)+4*(l>>5) (m74/m101 verified);
// A/B: lane holds row/col l&31, k = (l>>5)*8+e (family-consistent w/ m89).
// Swizzle: reads want 16B-group ((ks<<1)|h) ^ (row&7) -> same involution as
// R9/R10 staging (0 conflicts measured): bank walk = 32 lanes x 4 words
// spread over all 32 banks.
template <int EPI>  // 0 = bias->bf16; 1 = bias+res->f32; 2 = bias+GELU->bf16
__global__ __launch_bounds__(512) void gemm32(const unsigned short* __restrict__ A,
                                              const unsigned short* __restrict__ W,
                                              const float* __restrict__ bias,
                                              const float* __restrict__ res,
                                              unsigned short* __restrict__ outb,
                                              float* __restrict__ outf,
                                              int N, int K) {
  __shared__ unsigned short lds[3 * (128 + 256) * 64];  // 144 KiB
  const int tid = threadIdx.x;
  const int w = tid >> 6, l = tid & 63;
  const int m0 = blockIdx.y * 128, n0 = blockIdx.x * 256;
  const int wm = w >> 2, wn = w & 3;   // 2M x 4N waves, per-wave 64x64
  const int l31 = l & 31;
  const int h = l >> 5;                // k-half
  const int b7 = l & 7;                // row&7 for all frag rows

  const int ASLOT = 128 * 64;   // shorts
  const int B0 = 3 * ASLOT;
  const int BSLOT = 256 * 64;

  // hoisted frag read offsets (shorts, slot-relative). am/bn add 32 rows =
  // +2048 shorts (imm). gk(ks) = swizzled 16B-group ((ks<<1)|h) ^ b7.
  int baseA[4], baseB[4];
#pragma unroll
  for (int ks = 0; ks < 4; ++ks) {
    const int gk = ((((ks << 1) | h) ^ b7) * 8);
    baseA[ks] = (wm * 64 + l31) * 64 + gk;
    baseB[ks] = (wn * 64 + l31) * 64 + gk;
  }

  // staging (verbatim R10): dest linear, src col pre-swizzled.
  const int sr = tid >> 3;
  const int sx = ((tid & 7) ^ (sr & 7)) << 3;
  auto stA = [&](int t, int s, int hh) {
    gld_lds16(A + (size_t)(m0 + hh * 64 + sr) * K + t * 64 + sx,
              &lds[s * ASLOT + hh * 4096 + tid * 8]);
  };
  auto stB = [&](int t, int s, int c) {
    gld_lds16(W + (size_t)(n0 + c * 64 + sr) * K + t * 64 + sx,
              &lds[B0 + s * BSLOT + c * 4096 + tid * 8]);
  };

  f32x16 acc[2][2];
#pragma unroll
  for (int i = 0; i < 2; ++i)
#pragma unroll
    for (int j = 0; j < 2; ++j)
#pragma unroll
      for (int e = 0; e < 16; ++e) acc[i][j][e] = 0.f;

  bf16x8 af[2][2], bfr[2][2];  // [am/bn][kss] for the current 2-kstep phase

  // prologue: tiles 0,1 staged; VMW(6) -> tile 0 landed, tile 1 in flight
  stA(0, 0, 0); stA(0, 0, 1);
  stB(0, 0, 0); stB(0, 0, 1); stB(0, 0, 2); stB(0, 0, 3);
  stA(1, 1, 0); stA(1, 1, 1);
  stB(1, 1, 0); stB(1, 1, 1); stB(1, 1, 2); stB(1, 1, 3);
  VMW(6);
  BAR();

#define RD_PH(PH, SOFA, SOFB)                                                 \
  do {                                                                        \
    _Pragma("unroll") for (int am_ = 0; am_ < 2; ++am_)                       \
    _Pragma("unroll") for (int kk_ = 0; kk_ < 2; ++kk_)                       \
      af[am_][kk_] = *reinterpret_cast<const bf16x8*>(                        \
          &lds[(SOFA) + baseA[(PH) * 2 + kk_] + am_ * 2048]);                 \
    _Pragma("unroll") for (int bn_ = 0; bn_ < 2; ++bn_)                       \
    _Pragma("unroll") for (int kk_ = 0; kk_ < 2; ++kk_)                       \
      bfr[bn_][kk_] = *reinterpret_cast<const bf16x8*>(                       \
          &lds[(SOFB) + baseB[(PH) * 2 + kk_] + bn_ * 2048]);                 \
  } while (0)

#define MMA_PH()                                                              \
  do {                                                                        \
    _Pragma("unroll") for (int kk_ = 0; kk_ < 2; ++kk_)                       \
    _Pragma("unroll") for (int am_ = 0; am_ < 2; ++am_)                       \
    _Pragma("unroll") for (int bn_ = 0; bn_ < 2; ++bn_)                       \
      acc[am_][bn_] = __builtin_amdgcn_mfma_f32_32x32x16_bf16(                \
          af[am_][kk_], bfr[bn_][kk_], acc[am_][bn_], 0, 0, 0);               \
  } while (0)

  const int nt = K / 64;
  int s = 0, sp = 2;
  for (int t = 0; t < nt - 2; ++t) {
    const int tp2 = t + 2;
    const int sA = s * ASLOT, sB = B0 + s * BSLOT;
    // ph_a: ksteps 0,1 (8 ds_read, 8 MFMA); stage A(t+2) + B(t+2) c0/c1
    RD_PH(0, sA, sB);
    stA(tp2, sp, 0); stA(tp2, sp, 1);
    stB(tp2, sp, 0); stB(tp2, sp, 1);
    BAR(); LGKM0(); PRIO(1); MMA_PH(); PRIO(0); BAR();
    // ph_b: ksteps 2,3; stage B(t+2) c2/c3
    RD_PH(1, sA, sB);
    stB(tp2, sp, 2); stB(tp2, sp, 3);
    BAR(); LGKM0(); PRIO(1); MMA_PH(); PRIO(0);
    VMW(6);  // retire tile t+1's 6 (oldest); leave t+2's 6 in flight
    BAR();
    s = (s == 2) ? 0 : s + 1;
    sp = (sp == 2) ? 0 : sp + 1;
  }
  // tile nt-2: no staging; drain tile nt-1's loads at the end
  {
    const int sA = s * ASLOT, sB = B0 + s * BSLOT;
    RD_PH(0, sA, sB);
    BAR(); LGKM0(); PRIO(1); MMA_PH(); PRIO(0); BAR();
    RD_PH(1, sA, sB);
    BAR(); LGKM0(); PRIO(1); MMA_PH(); PRIO(0);
    VMW(0);
    BAR();
    s = (s == 2) ? 0 : s + 1;
  }
  // tile nt-1: clean compute
  {
    const int sA = s * ASLOT, sB = B0 + s * BSLOT;
    RD_PH(0, sA, sB);
    BAR(); LGKM0(); PRIO(1); MMA_PH(); PRIO(0); BAR();
    RD_PH(1, sA, sB);
    LGKM0(); PRIO(1); MMA_PH(); PRIO(0);
  }
#undef RD_PH
#undef MMA_PH

  // epilogue: 32x32 C layout col=l&31, row=(reg&3)+8*(reg>>2)+4*h (m74/m101)
#pragma unroll
  for (int bn = 0; bn < 2; ++bn) {
    const int col = n0 + wn * 64 + bn * 32 + l31;
    const float bv = bias[col];
#pragma unroll
    for (int am = 0; am < 2; ++am) {
#pragma unroll
      for (int reg = 0; reg < 16; ++reg) {
        const int row = m0 + wm * 64 + am * 32 + (reg & 3) + 8 * (reg >> 2) + 4 * h;
        const size_t idx = (size_t)row * N + col;
        float v = acc[am][bn][reg] + bv;
        if (EPI == 0) {
          outb[idx] = f2bf_bits(v);
        } else if (EPI == 1) {
          outf[idx] = v + res[idx];
        } else {
          v = 0.5f * v * (1.0f + erff(v * 0.70710678118654752f));
          outb[idx] = f2bf_bits(v);
        }
      }
    }
  }
}

// ---------------- causal flash attention v2 (paired q-tiles) ----------------
__device__ inline int swz(int row, int colelem) {
  return row * 64 + (colelem ^ ((row & 7) << 3));
}

__global__ __launch_bounds__(256) void attn_kernel(const unsigned short* __restrict__ kqv,
                                                   unsigned short* __restrict__ y) {
  __shared__ unsigned short Ks[2][64 * 64];
  __shared__ unsigned short Vt[2][64 * 64];
  __shared__ unsigned short Ps[4][16 * 64];

  const int tid = threadIdx.x;
  const int wave = tid >> 6;
  const int lane = tid & 63;
  const int bh = blockIdx.x;
  const int pair = blockIdx.y;
  const int b = bh >> 4;
  const int h = bh & 15;
  const int lo = pair;
  const int hi = 15 - pair;
  const int bT = b * 1024;
  const int hoff = h * 192;

  auto loadq = [&](int q0t, bf16x8 (&qf)[2]) {
    const unsigned short* qp =
        kqv + (size_t)(bT + q0t + wave * 16 + (lane & 15)) * 3072 + hoff + 64 +
        (lane >> 4) * 8;
#pragma unroll
    for (int kk = 0; kk < 2; ++kk) {
      bf16x8 t = *reinterpret_cast<const bf16x8*>(qp + kk * 32);
#pragma unroll
      for (int e = 0; e < 8; ++e) t[e] = (bf16_t)((float)t[e] * 0.125f);
      qf[kk] = t;
    }
  };

  auto stageK = [&](int j0, int bufi) {
#pragma unroll
    for (int i = 0; i < 2; ++i) {
      const int off = i * 4096 + wave * 1024 + lane * 16;
      const int jr = off >> 7;
      const int ce = ((off & 127) >> 1) ^ ((jr & 7) << 3);
      gld_lds16(kqv + (size_t)(bT + j0 + jr) * 3072 + hoff + ce,
                &Ks[bufi][i * 2048 + wave * 512]);
    }
  };

  ushort8_t vreg0, vreg1;
  auto vload = [&](int j0) {
    const unsigned short* vp =
        kqv + (size_t)(bT + j0 + (tid & 63)) * 3072 + hoff + 128 + (tid >> 6) * 8;
    vreg0 = *reinterpret_cast<const ushort8_t*>(vp);
    vreg1 = *reinterpret_cast<const ushort8_t*>(vp + 32);
  };
  auto vwrite = [&](int bufi) {
    const int j = tid & 63;
    const int dg = tid >> 6;
#pragma unroll
    for (int e = 0; e < 8; ++e) Vt[bufi][swz(dg * 8 + e, j)] = vreg0[e];
#pragma unroll
    for (int e = 0; e < 8; ++e) Vt[bufi][swz((dg + 4) * 8 + e, j)] = vreg1[e];
  };

  auto compute = [&](const bf16x8 (&qf)[2], f32x4 (&acc_o)[4], float (&mr)[4],
                     float (&lr)[4], int q0t, int j0, bool diag, int cur) {
    f32x4 s[4];
#pragma unroll
    for (int nt = 0; nt < 4; ++nt) {
      f32x4 a = {0.f, 0.f, 0.f, 0.f};
#pragma unroll
      for (int kk = 0; kk < 2; ++kk) {
        const bf16x8 kf = *reinterpret_cast<const bf16x8*>(
            &Ks[cur][swz(nt * 16 + (lane & 15), kk * 32 + (lane >> 4) * 8)]);
        a = __builtin_amdgcn_mfma_f32_16x16x32_bf16(qf[kk], kf, a, 0, 0, 0);
      }
      s[nt] = a;
    }
#pragma unroll
    for (int r = 0; r < 4; ++r) {
      float mx = -1e30f;
      if (diag) {
        const int qg = q0t + wave * 16 + ((lane >> 4) << 2) + r;
#pragma unroll
        for (int nt = 0; nt < 4; ++nt) {
          const int jg = j0 + nt * 16 + (lane & 15);
          const float sv = (jg <= qg) ? s[nt][r] : -1e30f;
          s[nt][r] = sv;
          mx = fmaxf(mx, sv);
        }
      } else {
#pragma unroll
        for (int nt = 0; nt < 4; ++nt) mx = fmaxf(mx, s[nt][r]);
      }
#pragma unroll
      for (int xm = 1; xm < 16; xm <<= 1) mx = fmaxf(mx, __shfl_xor(mx, xm, 64));
      const float mnew = fmaxf(mr[r], mx);
      const float sc = exp2f((mr[r] - mnew) * LOG2E);
      mr[r] = mnew;
      float ssum = 0.f;
#pragma unroll
      for (int nt = 0; nt < 4; ++nt) {
        const float p = exp2f((s[nt][r] - mnew) * LOG2E);
        s[nt][r] = p;
        ssum += p;
      }
#pragma unroll
      for (int xm = 1; xm < 16; xm <<= 1) ssum += __shfl_xor(ssum, xm, 64);
      lr[r] = lr[r] * sc + ssum;
#pragma unroll
      for (int dt = 0; dt < 4; ++dt) acc_o[dt][r] *= sc;
    }
    unsigned short* Pw = &Ps[wave][0];
#pragma unroll
    for (int nt = 0; nt < 4; ++nt)
#pragma unroll
      for (int r = 0; r < 4; ++r)
        Pw[swz(((lane >> 4) << 2) + r, nt * 16 + (lane & 15))] = f2bf_bits(s[nt][r]);
#pragma unroll
    for (int kk = 0; kk < 2; ++kk) {
      const bf16x8 pf = *reinterpret_cast<const bf16x8*>(
          &Ps[wave][swz(lane & 15, kk * 32 + (lane >> 4) * 8)]);
#pragma unroll
      for (int dt = 0; dt < 4; ++dt) {
        const bf16x8 vf = *reinterpret_cast<const bf16x8*>(
            &Vt[cur][swz(dt * 16 + (lane & 15), kk * 32 + (lane >> 4) * 8)]);
        acc_o[dt] = __builtin_amdgcn_mfma_f32_16x16x32_bf16(pf, vf, acc_o[dt], 0, 0, 0);
      }
    }
  };

  auto writeo = [&](int q0t, f32x4 (&acc_o)[4], float (&lr)[4]) {
#pragma unroll
    for (int dt = 0; dt < 4; ++dt)
#pragma unroll
      for (int r = 0; r < 4; ++r) {
        const int qg = q0t + wave * 16 + ((lane >> 4) << 2) + r;
        y[(size_t)(bT + qg) * 1024 + h * 64 + dt * 16 + (lane & 15)] =
            f2bf_bits(acc_o[dt][r] / lr[r]);
      }
  };

  bf16x8 qf_l[2], qf_h[2];
  loadq(lo * 64, qf_l);
  loadq(hi * 64, qf_h);
  f32x4 acc_l[4], acc_h[4];
#pragma unroll
  for (int dt = 0; dt < 4; ++dt) {
    f32x4 z = {0.f, 0.f, 0.f, 0.f};
    acc_l[dt] = z;
    acc_h[dt] = z;
  }
  float mr_l[4] = {-1e30f, -1e30f, -1e30f, -1e30f};
  float mr_h[4] = {-1e30f, -1e30f, -1e30f, -1e30f};
  float lr_l[4] = {0.f, 0.f, 0.f, 0.f};
  float lr_h[4] = {0.f, 0.f, 0.f, 0.f};

  stageK(0, 0);
  vload(0);
  vwrite(0);

  for (int jt = 0; jt <= hi; ++jt) {
    const int cur = jt & 1;
    __syncthreads();  // drains vmcnt/lgkm: buf[cur] ready; buf[cur^1] free
    if (jt < hi) {
      stageK((jt + 1) * 64, cur ^ 1);
      vload((jt + 1) * 64);
    }
    compute(qf_h, acc_h, mr_h, lr_h, hi * 64, jt * 64, jt == hi, cur);
    if (jt <= lo)
      compute(qf_l, acc_l, mr_l, lr_l, lo * 64, jt * 64, jt == lo, cur);
    if (jt < hi) vwrite(cur ^ 1);
  }

  writeo(hi * 64, acc_h, lr_h);
  writeo(lo * 64, acc_l, lr_l);
}

// ---------------- launch ----------------
extern "C" void kernel_launch(void* const* d_in, const int* in_sizes, int n_in,
                              void* d_out, int out_size, void* d_ws, size_t ws_size,
                              hipStream_t stream) {
  const float* x = (const float*)d_in[0];
  const float* kqv_w = (const float*)d_in[1];
  const float* kqv_b = (const float*)d_in[2];
  const float* proj_w = (const float*)d_in[3];
  const float* proj_b = (const float*)d_in[4];
  const float* ln1_g = (const float*)d_in[5];
  const float* ln1_b = (const float*)d_in[6];
  const float* ln2_g = (const float*)d_in[7];
  const float* ln2_b = (const float*)d_in[8];
  const float* fc1_w = (const float*)d_in[9];
  const float* fc1_b = (const float*)d_in[10];
  const float* fc2_w = (const float*)d_in[11];
  const float* fc2_b = (const float*)d_in[12];
  float* out = (float*)d_out;

  char* ws = (char*)d_ws;
  size_t off = 0;
  auto alloc = [&](size_t bytes) {
    char* p = ws + off;
    off += (bytes + 255) & ~(size_t)255;
    return p;
  };
  unsigned short* wk = (unsigned short*)alloc((size_t)3072 * 1024 * 2);
  unsigned short* wp = (unsigned short*)alloc((size_t)1024 * 1024 * 2);
  unsigned short* w1 = (unsigned short*)alloc((size_t)4096 * 1024 * 2);
  unsigned short* w2 = (unsigned short*)alloc((size_t)4096 * 1024 * 2);
  unsigned short* hbuf = (unsigned short*)alloc((size_t)8192 * 1024 * 2);
  unsigned short* kqvb = (unsigned short*)alloc((size_t)8192 * 3072 * 2);
  unsigned short* yb = (unsigned short*)alloc((size_t)8192 * 1024 * 2);
  float* x1 = (float*)alloc((size_t)8192 * 1024 * 4);
  unsigned short* a1 = (unsigned short*)alloc((size_t)8192 * 4096 * 2);

  // cast weights to bf16
  cast_kernel<<<dim3(3072 * 1024 / 1024), 256, 0, stream>>>(kqv_w, wk, 3072 * 1024);
  cast_kernel<<<dim3(1024 * 1024 / 1024), 256, 0, stream>>>(proj_w, wp, 1024 * 1024);
  cast_kernel<<<dim3(4096 * 1024 / 1024), 256, 0, stream>>>(fc1_w, w1, 4096 * 1024);
  cast_kernel<<<dim3(4096 * 1024 / 1024), 256, 0, stream>>>(fc2_w, w2, 4096 * 1024);

  // LN1 -> h (bf16)
  ln_kernel<<<dim3(8192), 256, 0, stream>>>(x, ln1_g, ln1_b, hbuf);

  // kqv = h @ kqv_w^T + b   [8192 x 3072]   grid (12,64)=768
  gemm32<0><<<dim3(3072 / 256, 8192 / 128), 512, 0, stream>>>(
      hbuf, wk, kqv_b, nullptr, kqvb, nullptr, 3072, 1024);

  // attention -> y (bf16)
  attn_kernel<<<dim3(128, 8), 256, 0, stream>>>(kqvb, yb);

  // x1 = x + y @ proj_w^T + b   (fp32)   grid (4,64)=256
  gemm32<1><<<dim3(1024 / 256, 8192 / 128), 512, 0, stream>>>(
      yb, wp, proj_b, x, nullptr, x1, 1024, 1024);

  // LN2 -> h (bf16, reuse)
  ln_kernel<<<dim3(8192), 256, 0, stream>>>(x1, ln2_g, ln2_b, hbuf);

  // a1 = gelu(h @ fc1_w^T + b)  [8192 x 4096]   grid (16,64)=1024
  gemm32<2><<<dim3(4096 / 256, 8192 / 128), 512, 0, stream>>>(
      hbuf, w1, fc1_b, nullptr, a1, nullptr, 4096, 1024);

  // out = x1 + a1 @ fc2_w^T + b  (fp32)  grid (4,64)=256, K=4096
  gemm32<1><<<dim3(1024 / 256, 8192 / 128), 512, 0, stream>>>(
      a1, w2, fc2_b, x1, nullptr, out, 1024, 4096);
}

// Round 16
// 422.869 us; speedup vs baseline: 1.1289x; 1.0859x over previous
//
#include <hip/hip_runtime.h>
#include <math.h>
#include <stdint.h>

typedef __bf16 bf16_t;
typedef __bf16 bf16x8 __attribute__((ext_vector_type(8)));
typedef float f32x4 __attribute__((ext_vector_type(4)));
typedef unsigned short ushort8_t __attribute__((ext_vector_type(8)));
typedef unsigned short ushort4_t __attribute__((ext_vector_type(4)));

#define LOG2E 1.44269504088896340736f

__device__ inline unsigned short f2bf_bits(float f) {
  union { float f; unsigned int u; } v; v.f = f;
  unsigned int u = v.u;
  return (unsigned short)((u + 0x7fffu + ((u >> 16) & 1u)) >> 16);
}

// global -> LDS direct copy, 16B per lane. LDS dest is wave-uniform base
// + lane*16 (HW behavior, m104); global src is per-lane.
__device__ inline void gld_lds16(const void* g, void* l) {
  __builtin_amdgcn_global_load_lds(
      (__attribute__((address_space(1))) void*)(uintptr_t)(g),
      (__attribute__((address_space(3))) void*)(uintptr_t)(l),
      16, 0, 0);
}

// ---------------- cast fp32 -> bf16 (weights) ----------------
__global__ __launch_bounds__(256) void cast_kernel(const float* __restrict__ in,
                                                   unsigned short* __restrict__ out,
                                                   int n) {
  int i = (blockIdx.x * 256 + threadIdx.x) * 4;
  if (i >= n) return;
  float4 f = *reinterpret_cast<const float4*>(in + i);
  ushort4_t o;
  o[0] = f2bf_bits(f.x); o[1] = f2bf_bits(f.y);
  o[2] = f2bf_bits(f.z); o[3] = f2bf_bits(f.w);
  *reinterpret_cast<ushort4_t*>(out + i) = o;
}

// ---------------- LayerNorm (C=1024) + cast to bf16 ----------------
__global__ __launch_bounds__(256) void ln_kernel(const float* __restrict__ x,
                                                 const float* __restrict__ g,
                                                 const float* __restrict__ bta,
                                                 unsigned short* __restrict__ out) {
  const int row = blockIdx.x;
  const int c = threadIdx.x * 4;
  const float4 xv = *reinterpret_cast<const float4*>(x + (size_t)row * 1024 + c);
  float s = xv.x + xv.y + xv.z + xv.w;
  float sq = xv.x * xv.x + xv.y * xv.y + xv.z * xv.z + xv.w * xv.w;
#pragma unroll
  for (int xm = 1; xm < 64; xm <<= 1) {
    s += __shfl_xor(s, xm, 64);
    sq += __shfl_xor(sq, xm, 64);
  }
  __shared__ float sh[8];
  const int wave = threadIdx.x >> 6, lane = threadIdx.x & 63;
  if (lane == 0) { sh[wave] = s; sh[4 + wave] = sq; }
  __syncthreads();
  const float ts = sh[0] + sh[1] + sh[2] + sh[3];
  const float tq = sh[4] + sh[5] + sh[6] + sh[7];
  const float mean = ts * (1.0f / 1024.0f);
  const float var = tq * (1.0f / 1024.0f) - mean * mean;
  const float rstd = rsqrtf(var + 1e-5f);
  const float4 gv = *reinterpret_cast<const float4*>(g + c);
  const float4 bv = *reinterpret_cast<const float4*>(bta + c);
  ushort4_t o;
  o[0] = f2bf_bits((xv.x - mean) * rstd * gv.x + bv.x);
  o[1] = f2bf_bits((xv.y - mean) * rstd * gv.y + bv.y);
  o[2] = f2bf_bits((xv.z - mean) * rstd * gv.z + bv.z);
  o[3] = f2bf_bits((xv.w - mean) * rstd * gv.w + bv.w);
  *reinterpret_cast<ushort4_t*>(out + (size_t)row * 1024 + c) = o;
}

// ---------------- GEMM m97-build-replica (R16) ------------------------------
// R15 post-mortem: 32x32 MFMA null (525 TF, +8.4M conflicts) -> issue-slot
// theory dead. Collated knob data across R5-R15: every launch_bounds /
// waves_per_eu combination yields a VGPR budget of 64-128; m97 (874 TF, SAME
// source structure) compiled to VGPR 164 + AGPR 64 — a rich budget that lets
// the scheduler keep wide ds_read->MFMA live ranges. m97 was built WITHOUT
// launch_bounds and WITH compile-time shapes. R16 replicates the build
// conditions on the best-total structure (R12 gemmS):
//   (a) NO __launch_bounds__ — allocator picks its own (m97-like) budget;
//   (b) N,K compile-time template constants (address math folds, trip count
//       known).
// Structure = R12 verbatim: 128^2 tile, 4 waves (2Mx2N), per-wave 64x64,
// BK=64, single 32 KiB LDS buffer, plain __syncthreads, compiler-scheduled
// inner loop, XOR swizzle (0 conflicts measured R12), no inline asm.
template <int EPI, int NN, int KK>  // EPI: 0 bias->bf16; 1 bias+res->f32; 2 bias+GELU->bf16
__global__ void gemmS(const unsigned short* __restrict__ A,
                      const unsigned short* __restrict__ W,
                      const float* __restrict__ bias,
                      const float* __restrict__ res,
                      unsigned short* __restrict__ outb,
                      float* __restrict__ outf) {
  __shared__ unsigned short lds[2 * 128 * 64];  // 32 KiB: A then B
  const int tid = threadIdx.x;
  const int wave = tid >> 6, l = tid & 63;
  const int m0 = blockIdx.y * 128, n0 = blockIdx.x * 128;
  const int wm = wave >> 1, wn = wave & 1;   // 2x2 wave grid
  const int lr16 = l & 15, lk = l >> 4;
  const int axor = (lr16 & 7) << 3;          // read-side XOR (row&7 == lr16&7)
  const int B0 = 128 * 64;

  // staging: 256 threads cover 32 rows x 64 elems per call (16B/thread).
  // dest row = tid>>3 (linear); src col pre-swizzled with the read involution.
  const int sr = tid >> 3;
  const int sx = ((tid & 7) ^ (sr & 7)) << 3;

  f32x4 acc[4][4];
#pragma unroll
  for (int i = 0; i < 4; ++i)
#pragma unroll
    for (int j = 0; j < 4; ++j) { f32x4 z = {0.f, 0.f, 0.f, 0.f}; acc[i][j] = z; }

  const int nt = KK / 64;
  for (int t = 0; t < nt; ++t) {
    // stage A[128][64] and B[128][64] for this K-tile (8 gld_lds per thread)
#pragma unroll
    for (int h = 0; h < 4; ++h)
      gld_lds16(A + (size_t)(m0 + h * 32 + sr) * KK + t * 64 + sx,
                &lds[h * 2048 + tid * 8]);
#pragma unroll
    for (int h = 0; h < 4; ++h)
      gld_lds16(W + (size_t)(n0 + h * 32 + sr) * KK + t * 64 + sx,
                &lds[B0 + h * 2048 + tid * 8]);
    __syncthreads();  // compiler emits the vmcnt/lgkm drain here

    bf16x8 af0[4], af1[4];
#pragma unroll
    for (int mi = 0; mi < 4; ++mi) {
      const int arow = (wm * 64 + mi * 16 + lr16) * 64;
      af0[mi] = *reinterpret_cast<const bf16x8*>(&lds[arow + ((lk * 8) ^ axor)]);
      af1[mi] = *reinterpret_cast<const bf16x8*>(&lds[arow + ((32 + lk * 8) ^ axor)]);
    }
#pragma unroll
    for (int ni = 0; ni < 4; ++ni) {
      const int brow = (wn * 64 + ni * 16 + lr16) * 64;
      const bf16x8 b0 = *reinterpret_cast<const bf16x8*>(
          &lds[B0 + brow + ((lk * 8) ^ axor)]);
      const bf16x8 b1 = *reinterpret_cast<const bf16x8*>(
          &lds[B0 + brow + ((32 + lk * 8) ^ axor)]);
#pragma unroll
      for (int mi = 0; mi < 4; ++mi) {
        acc[mi][ni] =
            __builtin_amdgcn_mfma_f32_16x16x32_bf16(af0[mi], b0, acc[mi][ni], 0, 0, 0);
        acc[mi][ni] =
            __builtin_amdgcn_mfma_f32_16x16x32_bf16(af1[mi], b1, acc[mi][ni], 0, 0, 0);
      }
    }
    __syncthreads();  // all reads done before next tile's gld_lds overwrites
  }

  // epilogue: C row=(l>>4)*4+r, col=l&15 per 16x16 fragment (m89/m91)
#pragma unroll
  for (int ni = 0; ni < 4; ++ni) {
    const int col = n0 + wn * 64 + ni * 16 + lr16;
    const float bv = bias[col];
#pragma unroll
    for (int mi = 0; mi < 4; ++mi) {
#pragma unroll
      for (int r = 0; r < 4; ++r) {
        const int row = m0 + wm * 64 + mi * 16 + lk * 4 + r;
        const size_t idx = (size_t)row * NN + col;
        float v = acc[mi][ni][r] + bv;
        if (EPI == 0) {
          outb[idx] = f2bf_bits(v);
        } else if (EPI == 1) {
          outf[idx] = v + res[idx];
        } else {
          v = 0.5f * v * (1.0f + erff(v * 0.70710678118654752f));
          outb[idx] = f2bf_bits(v);
        }
      }
    }
  }
}

// ---------------- causal flash attention v2 (paired q-tiles) ----------------
__device__ inline int swz(int row, int colelem) {
  return row * 64 + (colelem ^ ((row & 7) << 3));
}

__global__ __launch_bounds__(256) void attn_kernel(const unsigned short* __restrict__ kqv,
                                                   unsigned short* __restrict__ y) {
  __shared__ unsigned short Ks[2][64 * 64];
  __shared__ unsigned short Vt[2][64 * 64];
  __shared__ unsigned short Ps[4][16 * 64];

  const int tid = threadIdx.x;
  const int wave = tid >> 6;
  const int lane = tid & 63;
  const int bh = blockIdx.x;
  const int pair = blockIdx.y;
  const int b = bh >> 4;
  const int h = bh & 15;
  const int lo = pair;
  const int hi = 15 - pair;
  const int bT = b * 1024;
  const int hoff = h * 192;

  auto loadq = [&](int q0t, bf16x8 (&qf)[2]) {
    const unsigned short* qp =
        kqv + (size_t)(bT + q0t + wave * 16 + (lane & 15)) * 3072 + hoff + 64 +
        (lane >> 4) * 8;
#pragma unroll
    for (int kk = 0; kk < 2; ++kk) {
      bf16x8 t = *reinterpret_cast<const bf16x8*>(qp + kk * 32);
#pragma unroll
      for (int e = 0; e < 8; ++e) t[e] = (bf16_t)((float)t[e] * 0.125f);
      qf[kk] = t;
    }
  };

  auto stageK = [&](int j0, int bufi) {
#pragma unroll
    for (int i = 0; i < 2; ++i) {
      const int off = i * 4096 + wave * 1024 + lane * 16;
      const int jr = off >> 7;
      const int ce = ((off & 127) >> 1) ^ ((jr & 7) << 3);
      gld_lds16(kqv + (size_t)(bT + j0 + jr) * 3072 + hoff + ce,
                &Ks[bufi][i * 2048 + wave * 512]);
    }
  };

  ushort8_t vreg0, vreg1;
  auto vload = [&](int j0) {
    const unsigned short* vp =
        kqv + (size_t)(bT + j0 + (tid & 63)) * 3072 + hoff + 128 + (tid >> 6) * 8;
    vreg0 = *reinterpret_cast<const ushort8_t*>(vp);
    vreg1 = *reinterpret_cast<const ushort8_t*>(vp + 32);
  };
  auto vwrite = [&](int bufi) {
    const int j = tid & 63;
    const int dg = tid >> 6;
#pragma unroll
    for (int e = 0; e < 8; ++e) Vt[bufi][swz(dg * 8 + e, j)] = vreg0[e];
#pragma unroll
    for (int e = 0; e < 8; ++e) Vt[bufi][swz((dg + 4) * 8 + e, j)] = vreg1[e];
  };

  auto compute = [&](const bf16x8 (&qf)[2], f32x4 (&acc_o)[4], float (&mr)[4],
                     float (&lr)[4], int q0t, int j0, bool diag, int cur) {
    f32x4 s[4];
#pragma unroll
    for (int nt = 0; nt < 4; ++nt) {
      f32x4 a = {0.f, 0.f, 0.f, 0.f};
#pragma unroll
      for (int kk = 0; kk < 2; ++kk) {
        const bf16x8 kf = *reinterpret_cast<const bf16x8*>(
            &Ks[cur][swz(nt * 16 + (lane & 15), kk * 32 + (lane >> 4) * 8)]);
        a = __builtin_amdgcn_mfma_f32_16x16x32_bf16(qf[kk], kf, a, 0, 0, 0);
      }
      s[nt] = a;
    }
#pragma unroll
    for (int r = 0; r < 4; ++r) {
      float mx = -1e30f;
      if (diag) {
        const int qg = q0t + wave * 16 + ((lane >> 4) << 2) + r;
#pragma unroll
        for (int nt = 0; nt < 4; ++nt) {
          const int jg = j0 + nt * 16 + (lane & 15);
          const float sv = (jg <= qg) ? s[nt][r] : -1e30f;
          s[nt][r] = sv;
          mx = fmaxf(mx, sv);
        }
      } else {
#pragma unroll
        for (int nt = 0; nt < 4; ++nt) mx = fmaxf(mx, s[nt][r]);
      }
#pragma unroll
      for (int xm = 1; xm < 16; xm <<= 1) mx = fmaxf(mx, __shfl_xor(mx, xm, 64));
      const float mnew = fmaxf(mr[r], mx);
      const float sc = exp2f((mr[r] - mnew) * LOG2E);
      mr[r] = mnew;
      float ssum = 0.f;
#pragma unroll
      for (int nt = 0; nt < 4; ++nt) {
        const float p = exp2f((s[nt][r] - mnew) * LOG2E);
        s[nt][r] = p;
        ssum += p;
      }
#pragma unroll
      for (int xm = 1; xm < 16; xm <<= 1) ssum += __shfl_xor(ssum, xm, 64);
      lr[r] = lr[r] * sc + ssum;
#pragma unroll
      for (int dt = 0; dt < 4; ++dt) acc_o[dt][r] *= sc;
    }
    unsigned short* Pw = &Ps[wave][0];
#pragma unroll
    for (int nt = 0; nt < 4; ++nt)
#pragma unroll
      for (int r = 0; r < 4; ++r)
        Pw[swz(((lane >> 4) << 2) + r, nt * 16 + (lane & 15))] = f2bf_bits(s[nt][r]);
#pragma unroll
    for (int kk = 0; kk < 2; ++kk) {
      const bf16x8 pf = *reinterpret_cast<const bf16x8*>(
          &Ps[wave][swz(lane & 15, kk * 32 + (lane >> 4) * 8)]);
#pragma unroll
      for (int dt = 0; dt < 4; ++dt) {
        const bf16x8 vf = *reinterpret_cast<const bf16x8*>(
            &Vt[cur][swz(dt * 16 + (lane & 15), kk * 32 + (lane >> 4) * 8)]);
        acc_o[dt] = __builtin_amdgcn_mfma_f32_16x16x32_bf16(pf, vf, acc_o[dt], 0, 0, 0);
      }
    }
  };

  auto writeo = [&](int q0t, f32x4 (&acc_o)[4], float (&lr)[4]) {
#pragma unroll
    for (int dt = 0; dt < 4; ++dt)
#pragma unroll
      for (int r = 0; r < 4; ++r) {
        const int qg = q0t + wave * 16 + ((lane >> 4) << 2) + r;
        y[(size_t)(bT + qg) * 1024 + h * 64 + dt * 16 + (lane & 15)] =
            f2bf_bits(acc_o[dt][r] / lr[r]);
      }
  };

  bf16x8 qf_l[2], qf_h[2];
  loadq(lo * 64, qf_l);
  loadq(hi * 64, qf_h);
  f32x4 acc_l[4], acc_h[4];
#pragma unroll
  for (int dt = 0; dt < 4; ++dt) {
    f32x4 z = {0.f, 0.f, 0.f, 0.f};
    acc_l[dt] = z;
    acc_h[dt] = z;
  }
  float mr_l[4] = {-1e30f, -1e30f, -1e30f, -1e30f};
  float mr_h[4] = {-1e30f, -1e30f, -1e30f, -1e30f};
  float lr_l[4] = {0.f, 0.f, 0.f, 0.f};
  float lr_h[4] = {0.f, 0.f, 0.f, 0.f};

  stageK(0, 0);
  vload(0);
  vwrite(0);

  for (int jt = 0; jt <= hi; ++jt) {
    const int cur = jt & 1;
    __syncthreads();  // drains vmcnt/lgkm: buf[cur] ready; buf[cur^1] free
    if (jt < hi) {
      stageK((jt + 1) * 64, cur ^ 1);
      vload((jt + 1) * 64);
    }
    compute(qf_h, acc_h, mr_h, lr_h, hi * 64, jt * 64, jt == hi, cur);
    if (jt <= lo)
      compute(qf_l, acc_l, mr_l, lr_l, lo * 64, jt * 64, jt == lo, cur);
    if (jt < hi) vwrite(cur ^ 1);
  }

  writeo(hi * 64, acc_h, lr_h);
  writeo(lo * 64, acc_l, lr_l);
}

// ---------------- launch ----------------
extern "C" void kernel_launch(void* const* d_in, const int* in_sizes, int n_in,
                              void* d_out, int out_size, void* d_ws, size_t ws_size,
                              hipStream_t stream) {
  const float* x = (const float*)d_in[0];
  const float* kqv_w = (const float*)d_in[1];
  const float* kqv_b = (const float*)d_in[2];
  const float* proj_w = (const float*)d_in[3];
  const float* proj_b = (const float*)d_in[4];
  const float* ln1_g = (const float*)d_in[5];
  const float* ln1_b = (const float*)d_in[6];
  const float* ln2_g = (const float*)d_in[7];
  const float* ln2_b = (const float*)d_in[8];
  const float* fc1_w = (const float*)d_in[9];
  const float* fc1_b = (const float*)d_in[10];
  const float* fc2_w = (const float*)d_in[11];
  const float* fc2_b = (const float*)d_in[12];
  float* out = (float*)d_out;

  char* ws = (char*)d_ws;
  size_t off = 0;
  auto alloc = [&](size_t bytes) {
    char* p = ws + off;
    off += (bytes + 255) & ~(size_t)255;
    return p;
  };
  unsigned short* wk = (unsigned short*)alloc((size_t)3072 * 1024 * 2);
  unsigned short* wp = (unsigned short*)alloc((size_t)1024 * 1024 * 2);
  unsigned short* w1 = (unsigned short*)alloc((size_t)4096 * 1024 * 2);
  unsigned short* w2 = (unsigned short*)alloc((size_t)4096 * 1024 * 2);
  unsigned short* hbuf = (unsigned short*)alloc((size_t)8192 * 1024 * 2);
  unsigned short* kqvb = (unsigned short*)alloc((size_t)8192 * 3072 * 2);
  unsigned short* yb = (unsigned short*)alloc((size_t)8192 * 1024 * 2);
  float* x1 = (float*)alloc((size_t)8192 * 1024 * 4);
  unsigned short* a1 = (unsigned short*)alloc((size_t)8192 * 4096 * 2);

  // cast weights to bf16
  cast_kernel<<<dim3(3072 * 1024 / 1024), 256, 0, stream>>>(kqv_w, wk, 3072 * 1024);
  cast_kernel<<<dim3(1024 * 1024 / 1024), 256, 0, stream>>>(proj_w, wp, 1024 * 1024);
  cast_kernel<<<dim3(4096 * 1024 / 1024), 256, 0, stream>>>(fc1_w, w1, 4096 * 1024);
  cast_kernel<<<dim3(4096 * 1024 / 1024), 256, 0, stream>>>(fc2_w, w2, 4096 * 1024);

  // LN1 -> h (bf16)
  ln_kernel<<<dim3(8192), 256, 0, stream>>>(x, ln1_g, ln1_b, hbuf);

  // kqv = h @ kqv_w^T + b   [8192 x 3072]   grid (24,64)
  gemmS<0, 3072, 1024><<<dim3(3072 / 128, 8192 / 128), 256, 0, stream>>>(
      hbuf, wk, kqv_b, nullptr, kqvb, nullptr);

  // attention -> y (bf16)
  attn_kernel<<<dim3(128, 8), 256, 0, stream>>>(kqvb, yb);

  // x1 = x + y @ proj_w^T + b   (fp32)   grid (8,64)
  gemmS<1, 1024, 1024><<<dim3(1024 / 128, 8192 / 128), 256, 0, stream>>>(
      yb, wp, proj_b, x, nullptr, x1);

  // LN2 -> h (bf16, reuse)
  ln_kernel<<<dim3(8192), 256, 0, stream>>>(x1, ln2_g, ln2_b, hbuf);

  // a1 = gelu(h @ fc1_w^T + b)  [8192 x 4096]   grid (32,64)
  gemmS<2, 4096, 1024><<<dim3(4096 / 128, 8192 / 128), 256, 0, stream>>>(
      hbuf, w1, fc1_b, nullptr, a1, nullptr);

  // out = x1 + a1 @ fc2_w^T + b  (fp32)  grid (8,64), K=4096
  gemmS<1, 1024, 4096><<<dim3(1024 / 128, 8192 / 128), 256, 0, stream>>>(
      a1, w2, fc2_b, x1, nullptr, out);
}